// Round 6
// baseline (28.883 us; speedup 1.0000x reference)
//
#include <hip/hip_runtime.h>

// CTRMultiEmbedding: joint embedding gather + bilinear interval embedding.
// out = [joint (B,L,D) | delta (B,L,L,D)] concatenated, float32.
// delta[b,i,j,d] = base[m][d] + ds*cs[m][d] + dt*ct[m][d]
//   m = (i<len_b && j<len_b); base = e_sl+e_tl, cs = e_su-e_sl, ct = e_tu-e_tl.
//
// Round 6: read/write phase separation on the round-1 layout (best so far,
// 27.1 us). All 16 mat loads issued as one burst into 32 VGPRs, then 16
// pure f4 stores back-to-back. Collective write front stays contiguous
// (2^19 threads advance an 8-MB window per unrolled step). Plain stores
// (NT regressed 2.5x). Coefficients staged LDS-once-per-block, then 6 f4
// registers (d-offset loop-invariant since stride 2^19 % 16 == 0).

typedef float f4 __attribute__((ext_vector_type(4)));
typedef float f2 __attribute__((ext_vector_type(2)));

constexpr int HOURS   = 168;
constexpr int Dd      = 64;
constexpr int NJOINT4 = 8 * 256 * 64 / 4;   // 32768 f4
constexpr int NJOINT  = NJOINT4 * 4;        // 131072 floats
constexpr int STRIDE4 = 524288;             // 2^19 f4, one full grid step
constexpr int KITERS  = 16;                 // 8388608 / 524288

__device__ __forceinline__ f4 ld4(const float* p) {
    return *reinterpret_cast<const f4*>(p);
}

__global__ __launch_bounds__(256) void ctr_fused_kernel(
    const int*   __restrict__ traj,     // (B,L,3) int32
    const float* __restrict__ mat,      // (B,L,L,2)
    const int*   __restrict__ lens,     // (B)
    const float* __restrict__ emb_t,    // (169,64)
    const float* __restrict__ emb_l,    // (50000,64)
    const float* __restrict__ emb_u,    // (10000,64)
    const float* __restrict__ emb_su,   // (2,64)
    const float* __restrict__ emb_sl,
    const float* __restrict__ emb_tu,
    const float* __restrict__ emb_tl,
    float* __restrict__ out)
{
    __shared__ float s_base[2][64], s_cs[2][64], s_ct[2][64];
    __shared__ int   s_len[8];

    const int tid = threadIdx.x;
    if (tid < 128) {
        int m = tid >> 6, d = tid & 63;
        float sl = emb_sl[tid], su = emb_su[tid];
        float tl = emb_tl[tid], tu = emb_tu[tid];
        s_base[m][d] = sl + tl;
        s_cs[m][d]   = su - sl;
        s_ct[m][d]   = tu - tl;
    }
    if (tid < 8) s_len[tid] = lens[tid];

    const int tid_g = blockIdx.x * 256 + tid;   // 0 .. 2^19-1
    const int dof   = (tid_g & 15) * 4;         // float offset in D, invariant

    // ---- phase 1: burst-issue all 16 mat loads (independent, in flight) ----
    f2 dd[KITERS];
#pragma unroll
    for (int k = 0; k < KITERS; ++k) {
        int pair = (tid_g + k * STRIDE4) >> 4;
        dd[k] = *reinterpret_cast<const f2*>(&mat[(size_t)pair * 2]);
    }

    // ---- joint embedding: first 32768 threads, one f4 each ----
    if (tid_g < NJOINT4) {
        int row  = tid_g >> 4;
        int user = traj[row * 3 + 0];
        int loc  = traj[row * 3 + 1];
        int t    = traj[row * 3 + 2];
        int tm = (t - 1) % HOURS;               // python modulo fixup
        if (tm < 0) tm += HOURS;
        int tx = tm + 1;
        f4 o = ld4(emb_t + tx * Dd + dof)
             + ld4(emb_l + loc * Dd + dof)
             + ld4(emb_u + user * Dd + dof);
        *reinterpret_cast<f4*>(&out[(size_t)tid_g * 4]) = o;
    }

    __syncthreads();   // s_* tables ready (also lets LDS stage overlap loads)

    // ---- coefficients -> 6 f4 registers ----
    const f4 base0 = ld4(&s_base[0][dof]), base1 = ld4(&s_base[1][dof]);
    const f4 cs0   = ld4(&s_cs[0][dof]),   cs1   = ld4(&s_cs[1][dof]);
    const f4 ct0   = ld4(&s_ct[0][dof]),   ct1   = ld4(&s_ct[1][dof]);

    // ---- phase 2: 16 pure stores, collective-contiguous 8-MB window/step ----
#pragma unroll
    for (int k = 0; k < KITERS; ++k) {
        int di   = tid_g + k * STRIDE4;
        int pair = di >> 4;                     // b*65536 + i*256 + j
        int b  = pair >> 16;
        int i  = (pair >> 8) & 255;
        int j  = pair & 255;
        int len = s_len[b];
        bool v = (i < len) && (j < len);
        f4 o = (v ? base1 : base0)
             + dd[k].x * (v ? cs1 : cs0)
             + dd[k].y * (v ? ct1 : ct0);
        *reinterpret_cast<f4*>(&out[NJOINT + (size_t)di * 4]) = o;
    }
}

extern "C" void kernel_launch(void* const* d_in, const int* in_sizes, int n_in,
                              void* d_out, int out_size, void* d_ws, size_t ws_size,
                              hipStream_t stream) {
    const int*   traj   = (const int*)  d_in[0];
    const float* mat    = (const float*)d_in[1];
    const int*   lens   = (const int*)  d_in[2];
    const float* emb_t  = (const float*)d_in[3];
    const float* emb_l  = (const float*)d_in[4];
    const float* emb_u  = (const float*)d_in[5];
    const float* emb_su = (const float*)d_in[6];
    const float* emb_sl = (const float*)d_in[7];
    const float* emb_tu = (const float*)d_in[8];
    const float* emb_tl = (const float*)d_in[9];
    float* out = (float*)d_out;

    ctr_fused_kernel<<<2048, 256, 0, stream>>>(
        traj, mat, lens, emb_t, emb_l, emb_u, emb_su, emb_sl, emb_tu, emb_tl, out);
}

// Round 7
// 26.985 us; speedup vs baseline: 1.0703x; 1.0703x over previous
//
#include <hip/hip_runtime.h>

// CTRMultiEmbedding: joint embedding gather + bilinear interval embedding.
// out = [joint (B,L,D) | delta (B,L,L,D)] concatenated, float32.
// delta[b,i,j,d] = base[m][d] + ds*cs[m][d] + dt*ct[m][d]
//   where m = (i<len_b && j<len_b), ds/dt = mat_input[b,i,j,0/1],
//   base = e_sl+e_tl, cs = e_su-e_sl, ct = e_tu-e_tl  (EX spans are 1).
//
// FINAL: round-1 structure, the best of six A/B'd variants (27.1 us vs
// 27.7-29.1 for reg-hoist / batch-unroll / wave-sequential / phase-split,
// 67 for NT stores). Plateau is the mixed-stream write floor: ~139 MB
// mandatory traffic at ~5.8+ TB/s edge-corrected, with ~2-3 us dispatch
// edges on a 27-us kernel. LDS conflicts 0, VALUBusy ~5% -> memory-bound.

constexpr int Bb = 8, Ll = 256, Dd = 64;
constexpr int HOURS = 168;
constexpr int NJOINT4 = Bb * Ll * Dd / 4;          // 32768 float4
constexpr int NPAIR   = Bb * Ll * Ll;              // 524288 (b,i,j) pairs
constexpr int NDELTA4 = NPAIR * Dd / 4;            // 8,388,608 float4
constexpr int NTOT4   = NJOINT4 + NDELTA4;

__global__ __launch_bounds__(256) void ctr_fused_kernel(
    const int*   __restrict__ traj,     // (B,L,3) int32
    const float* __restrict__ mat,      // (B,L,L,2)
    const int*   __restrict__ lens,     // (B)
    const float* __restrict__ emb_t,    // (169,64)
    const float* __restrict__ emb_l,    // (50000,64)
    const float* __restrict__ emb_u,    // (10000,64)
    const float* __restrict__ emb_su,   // (2,64)
    const float* __restrict__ emb_sl,
    const float* __restrict__ emb_tu,
    const float* __restrict__ emb_tl,
    float* __restrict__ out)
{
    __shared__ float s_base[2][64];
    __shared__ float s_cs[2][64];
    __shared__ float s_ct[2][64];
    __shared__ int   s_len[8];

    const int tid = threadIdx.x;
    if (tid < 128) {
        // tid = m*64 + d
        float sl = emb_sl[tid], su = emb_su[tid];
        float tl = emb_tl[tid], tu = emb_tu[tid];
        int m = tid >> 6, d = tid & 63;
        s_base[m][d] = sl + tl;
        s_cs[m][d]   = su - sl;
        s_ct[m][d]   = tu - tl;
    }
    if (tid < 8) s_len[tid] = lens[tid];
    __syncthreads();

    const int stride = gridDim.x * blockDim.x;
    for (int g = blockIdx.x * blockDim.x + tid; g < NTOT4; g += stride) {
        if (g < NJOINT4) {
            // ---- joint embedding: row = b*L + l, 16 float4 per row ----
            int row = g >> 4;
            int d4  = g & 15;
            int user = traj[row * 3 + 0];
            int loc  = traj[row * 3 + 1];
            int t    = traj[row * 3 + 2];
            // python modulo: (t-1) % 168 (handles t==0 -> 167), then +1
            int tm = (t - 1) % HOURS;
            if (tm < 0) tm += HOURS;
            int tidx = tm + 1;
            const float4 a = *reinterpret_cast<const float4*>(&emb_t[tidx * Dd + d4 * 4]);
            const float4 b = *reinterpret_cast<const float4*>(&emb_l[loc  * Dd + d4 * 4]);
            const float4 c = *reinterpret_cast<const float4*>(&emb_u[user * Dd + d4 * 4]);
            float4 o;
            o.x = a.x + b.x + c.x;
            o.y = a.y + b.y + c.y;
            o.z = a.z + b.z + c.z;
            o.w = a.w + b.w + c.w;
            *reinterpret_cast<float4*>(&out[g * 4]) = o;
        } else {
            // ---- delta embedding ----
            int di   = g - NJOINT4;
            int pair = di >> 4;            // b*65536 + i*256 + j
            int d4   = di & 15;
            int b  = pair >> 16;
            int i  = (pair >> 8) & 255;
            int j  = pair & 255;
            int len = s_len[b];
            int m = (i < len && j < len) ? 1 : 0;
            float2 dd = *reinterpret_cast<const float2*>(&mat[(size_t)pair * 2]);
            float ds = dd.x, dt = dd.y;
            const float4 bb = *reinterpret_cast<const float4*>(&s_base[m][d4 * 4]);
            const float4 cs = *reinterpret_cast<const float4*>(&s_cs[m][d4 * 4]);
            const float4 ct = *reinterpret_cast<const float4*>(&s_ct[m][d4 * 4]);
            float4 o;
            o.x = bb.x + ds * cs.x + dt * ct.x;
            o.y = bb.y + ds * cs.y + dt * ct.y;
            o.z = bb.z + ds * cs.z + dt * ct.z;
            o.w = bb.w + ds * cs.w + dt * ct.w;
            *reinterpret_cast<float4*>(&out[(size_t)NJOINT4 * 4 + (size_t)di * 4]) = o;
        }
    }
}

extern "C" void kernel_launch(void* const* d_in, const int* in_sizes, int n_in,
                              void* d_out, int out_size, void* d_ws, size_t ws_size,
                              hipStream_t stream) {
    const int*   traj   = (const int*)  d_in[0];
    const float* mat    = (const float*)d_in[1];
    const int*   lens   = (const int*)  d_in[2];
    const float* emb_t  = (const float*)d_in[3];
    const float* emb_l  = (const float*)d_in[4];
    const float* emb_u  = (const float*)d_in[5];
    const float* emb_su = (const float*)d_in[6];
    const float* emb_sl = (const float*)d_in[7];
    const float* emb_tu = (const float*)d_in[8];
    const float* emb_tl = (const float*)d_in[9];
    float* out = (float*)d_out;

    const int block = 256;
    const int grid  = 2048;   // ~8 blocks/CU, grid-stride over 8.4M float4
    ctr_fused_kernel<<<grid, block, 0, stream>>>(
        traj, mat, lens, emb_t, emb_l, emb_u, emb_su, emb_sl, emb_tu, emb_tl, out);
}